// Round 3
// baseline (459.796 us; speedup 1.0000x reference)
//
#include <hip/hip_runtime.h>
#include <hip/hip_bf16.h>
#include <stdint.h>

// ---------------------------------------------------------------------------
// SGI grid-GCN head on MI355X.  Round 3:
//  - Agg and GEMM commute for layer 1: xa = Agg(x) computed in prep (cheap
//    contiguous stencil in native [C][N] layout), then
//    h = relu(xa@W1 + b1) + xt folded into the gemm epilogue.
//    stencil1 and the g1 intermediate are GONE.
//  - dual-GEMM fusion reverted (it cost occupancy: VGPR 96, MfmaUtil -6pts).
//  - workspace aliasing: origin reuses xa slot, g2 reuses xt slot (~159 MB).
//  5 dispatches: prep, gemm_h, gemm_o, gemm2, stencil2.
// ---------------------------------------------------------------------------

typedef __bf16 bf16;
typedef float f32x4 __attribute__((ext_vector_type(4)));
typedef bf16 bf16x8 __attribute__((ext_vector_type(8)));

#define NB 4
#define NN 4096
#define CIN 1536
#define HIDF 1536
#define OUTF 512

__device__ __forceinline__ float degree_of(int n) {
  const int x = n & 63, y = n >> 6;
  return 1.0f + (x > 0) + (x < 63) + (y > 0) + (y < 63);
}

// ------------------------------- prep ---------------------------------------
// x [B][CIN][NN] fp32 -> xt [B][NN][CIN] bf16  AND  xa = Agg(x) same layout.
// Weights transposed+converted in the same dispatch.
__device__ __forceinline__ void tcvt(const float* __restrict__ in,
                                     bf16* __restrict__ out, int R, int Cc,
                                     int c0, int r0, int t,
                                     float (*tile)[33]) {
  const int tx = t & 31, ty = t >> 5;
#pragma unroll
  for (int i = 0; i < 4; i++)
    tile[ty + i * 8][tx] = in[(long)(r0 + ty + i * 8) * Cc + c0 + tx];
  __syncthreads();
#pragma unroll
  for (int i = 0; i < 4; i++)
    out[(long)(c0 + ty + i * 8) * R + r0 + tx] = (bf16)tile[tx][ty + i * 8];
}

#define XTILES (NB * (NN / 32) * (CIN / 32))          // 24576
#define W1TILES ((CIN / 32) * (HIDF / 32))            // 2304
#define W2TILES ((HIDF / 32) * (OUTF / 32))           // 768
#define WLTILES ((CIN / 32) * (OUTF / 32))            // 768

__global__ __launch_bounds__(256) void prep(
    const float* __restrict__ x, const float* __restrict__ W1,
    const float* __restrict__ W2, const float* __restrict__ Wl,
    bf16* __restrict__ xt, bf16* __restrict__ xa, bf16* __restrict__ w1t,
    bf16* __restrict__ w2t, bf16* __restrict__ wlt) {
  __shared__ float t1[32][33];
  __shared__ float t2[32][33];
  const int b = blockIdx.x, t = threadIdx.x;
  if (b < XTILES) {
    // x tile: compute plain transpose AND aggregated transpose.
    const int batch = b / (XTILES / NB), local = b % (XTILES / NB);
    const int ntile = (local & 127) * 32, ctile = (local >> 7) * 32;
    const float* inb = x + (long)batch * CIN * NN;
    const int tx = t & 31, ty = t >> 5;
    const int n = ntile + tx;
    const int gx = n & 63, gy = n >> 6;
    const float degn = degree_of(n);
    const float winv = 1.0f / degn;
    const float wL = (gx > 0) ? rsqrtf(degn * degree_of(n - 1)) : 0.f;
    const float wR = (gx < 63) ? rsqrtf(degn * degree_of(n + 1)) : 0.f;
    const float wU = (gy > 0) ? rsqrtf(degn * degree_of(n - 64)) : 0.f;
    const float wD = (gy < 63) ? rsqrtf(degn * degree_of(n + 64)) : 0.f;
#pragma unroll
    for (int i = 0; i < 4; i++) {
      const float* row = inb + (long)(ctile + ty + i * 8) * NN;
      const float v = row[n];
      float a = v * winv;
      if (gx > 0) a += row[n - 1] * wL;
      if (gx < 63) a += row[n + 1] * wR;
      if (gy > 0) a += row[n - 64] * wU;
      if (gy < 63) a += row[n + 64] * wD;
      t1[ty + i * 8][tx] = v;
      t2[ty + i * 8][tx] = a;
    }
    __syncthreads();
    bf16* xtb = xt + (long)batch * NN * CIN;
    bf16* xab = xa + (long)batch * NN * CIN;
#pragma unroll
    for (int i = 0; i < 4; i++) {
      const long o = (long)(ntile + ty + i * 8) * CIN + ctile + tx;
      xtb[o] = (bf16)t1[tx][ty + i * 8];
      xab[o] = (bf16)t2[tx][ty + i * 8];
    }
  } else if (b < XTILES + W1TILES) {      // W1 [CIN][HIDF] -> w1t [HIDF][CIN]
    const int local = b - XTILES;
    tcvt(W1, w1t, CIN, HIDF, (local % 48) * 32, (local / 48) * 32, t, t1);
  } else if (b < XTILES + W1TILES + W2TILES) {  // W2 -> w2t [OUTF][HIDF]
    const int local = b - XTILES - W1TILES;
    tcvt(W2, w2t, HIDF, OUTF, (local % 16) * 32, (local / 16) * 32, t, t1);
  } else {                                // Wl -> wlt [OUTF][CIN]
    const int local = b - XTILES - W1TILES - W2TILES;
    tcvt(Wl, wlt, CIN, OUTF, (local % 16) * 32, (local / 16) * 32, t, t1);
  }
}

// ------------------------------- GEMM core ---------------------------------
__device__ __forceinline__ void async_copy16(const void* g, void* l) {
  __builtin_amdgcn_global_load_lds(
      (const __attribute__((address_space(1))) void*)g,
      (__attribute__((address_space(3))) void*)l, 16, 0, 0);
}

struct GemmCtx {
  f32x4 acc[4][4];
  int wave, lane, wm, wn, quad, l15;
};

__device__ __forceinline__ void gemm_init(GemmCtx& cx, int t) {
  cx.wave = t >> 6;
  cx.lane = t & 63;
  cx.wm = (cx.wave & 1) * 64;
  cx.wn = (cx.wave >> 1) * 64;
  cx.quad = cx.lane >> 4;
  cx.l15 = cx.lane & 15;
#pragma unroll
  for (int i = 0; i < 4; i++)
#pragma unroll
    for (int j = 0; j < 4; j++) cx.acc[i][j] = {0.f, 0.f, 0.f, 0.f};
}

template <int K>
__device__ __forceinline__ void gemm_kloop(GemmCtx& cx, const bf16* Ab,
                                           const bf16* Bb, bf16* As,
                                           bf16* Bs) {
  const int r = cx.lane >> 3, c8 = cx.lane & 7;
  const int fchunk = c8 ^ r;
  for (int kt = 0; kt < K; kt += 64) {
#pragma unroll
    for (int i = 0; i < 4; i++) {
      const int row = i * 32 + cx.wave * 8;
      async_copy16(Ab + (long)(row + r) * K + kt + fchunk * 8, &As[row * 64]);
      async_copy16(Bb + (long)(row + r) * K + kt + fchunk * 8, &Bs[row * 64]);
    }
    __syncthreads();
#pragma unroll
    for (int kk = 0; kk < 2; kk++) {
      const int q = kk * 4 + cx.quad;
      bf16x8 af[4], bfv[4];
#pragma unroll
      for (int mr = 0; mr < 4; mr++) {
        const int m = cx.wm + mr * 16 + cx.l15;
        af[mr] = *(const bf16x8*)&As[m * 64 + (q ^ (m & 7)) * 8];
      }
#pragma unroll
      for (int nc = 0; nc < 4; nc++) {
        const int n = cx.wn + nc * 16 + cx.l15;
        bfv[nc] = *(const bf16x8*)&Bs[n * 64 + (q ^ (n & 7)) * 8];
      }
#pragma unroll
      for (int mr = 0; mr < 4; mr++)
#pragma unroll
        for (int nc = 0; nc < 4; nc++)
          cx.acc[mr][nc] = __builtin_amdgcn_mfma_f32_16x16x32_bf16(
              af[mr], bfv[nc], cx.acc[mr][nc], 0, 0, 0);
    }
    __syncthreads();
  }
}

// h = bf16( relu(xa @ w1t^T + b1) + xt )   [B][NN][HIDF]
__global__ __launch_bounds__(256) void gemm_h(
    const bf16* __restrict__ xa, const bf16* __restrict__ w1t,
    const bf16* __restrict__ xt, bf16* __restrict__ h,
    const float* __restrict__ b1) {
  __shared__ bf16 As[128 * 64];
  __shared__ bf16 Bs[128 * 64];
  GemmCtx cx;
  gemm_init(cx, threadIdx.x);
  const int m0 = blockIdx.x * 128, n0 = blockIdx.y * 128, z = blockIdx.z;
  gemm_kloop<CIN>(cx, xa + (long)z * NN * CIN + (long)m0 * CIN,
                  w1t + (long)n0 * CIN, As, Bs);
  const bf16* Xb = xt + (long)z * NN * HIDF;
  bf16* Cb = h + (long)z * NN * HIDF;
#pragma unroll
  for (int mr = 0; mr < 4; mr++)
#pragma unroll
    for (int nc = 0; nc < 4; nc++) {
      const int gn = n0 + cx.wn + nc * 16 + cx.l15;
      const float bv = b1[gn];
#pragma unroll
      for (int j = 0; j < 4; j++) {
        const int gm = m0 + cx.wm + mr * 16 + cx.quad * 4 + j;
        float v = cx.acc[mr][nc][j] + bv;
        v = v > 0.f ? v : 0.f;
        Cb[(long)gm * HIDF + gn] = (bf16)(v + (float)Xb[(long)gm * HIDF + gn]);
      }
    }
}

// fp32-out GEMM (gemm_o with bias, gemm2 without).
template <bool ADD_BIAS>
__global__ __launch_bounds__(256) void gemm_f32(
    const bf16* __restrict__ A, const bf16* __restrict__ Bw,
    float* __restrict__ C, const float* __restrict__ bias) {
  __shared__ bf16 As[128 * 64];
  __shared__ bf16 Bs[128 * 64];
  GemmCtx cx;
  gemm_init(cx, threadIdx.x);
  const int m0 = blockIdx.x * 128, n0 = blockIdx.y * 128, z = blockIdx.z;
  gemm_kloop<CIN>(cx, A + (long)z * NN * CIN + (long)m0 * CIN,
                  Bw + (long)n0 * CIN, As, Bs);
  float* Cb = C + (long)z * NN * OUTF;
#pragma unroll
  for (int mr = 0; mr < 4; mr++)
#pragma unroll
    for (int nc = 0; nc < 4; nc++) {
      const int gn = n0 + cx.wn + nc * 16 + cx.l15;
      float bv = 0.f;
      if (ADD_BIAS) bv = bias[gn];
#pragma unroll
      for (int j = 0; j < 4; j++) {
        const int gm = m0 + cx.wm + mr * 16 + cx.quad * 4 + j;
        Cb[(long)gm * OUTF + gn] = cx.acc[mr][nc][j] + bv;
      }
    }
}

// ------------------------------- stencil2 ----------------------------------
// out[b][f][n] = (Agg(G2)[n][f] + b2[f]) * Origin[n][f]; transpose via LDS.
__global__ __launch_bounds__(256) void stencil2(
    const float* __restrict__ G2, const float* __restrict__ Orig,
    const float* __restrict__ b2, float* __restrict__ out) {
  __shared__ float tile[16][513];
  const int blk = blockIdx.x;                        // 256 strips
  const int s = ((blk & 7) << 5) + (blk >> 3);       // XCD-contiguous
  const int n0 = s * 16, b = blockIdx.y;
  const int t = threadIdx.x;
  const int fq = t & 127, nl = t >> 7;
  const int f = fq * 4;
  const f32x4 bv = *(const f32x4*)(b2 + f);
#pragma unroll
  for (int p = 0; p < 8; p++) {
    const int nLoc = p * 2 + nl;
    const int n = n0 + nLoc;
    const int gx = n & 63, gy = n >> 6;
    const float degn = degree_of(n);
    const float ws = 1.0f / degn;
    const long rb = ((long)b * NN + n) * (long)OUTF + f;
    f32x4 g = *(const f32x4*)(G2 + rb);
    f32x4 a;
#pragma unroll
    for (int i = 0; i < 4; i++) a[i] = g[i] * ws;
    if (gx > 0) {
      const float w = rsqrtf(degn * degree_of(n - 1));
      f32x4 u = *(const f32x4*)(G2 + rb - OUTF);
#pragma unroll
      for (int i = 0; i < 4; i++) a[i] += u[i] * w;
    }
    if (gx < 63) {
      const float w = rsqrtf(degn * degree_of(n + 1));
      f32x4 u = *(const f32x4*)(G2 + rb + OUTF);
#pragma unroll
      for (int i = 0; i < 4; i++) a[i] += u[i] * w;
    }
    if (gy > 0) {
      const float w = rsqrtf(degn * degree_of(n - 64));
      f32x4 u = *(const f32x4*)(G2 + rb - 64L * OUTF);
#pragma unroll
      for (int i = 0; i < 4; i++) a[i] += u[i] * w;
    }
    if (gy < 63) {
      const float w = rsqrtf(degn * degree_of(n + 64));
      f32x4 u = *(const f32x4*)(G2 + rb + 64L * OUTF);
#pragma unroll
      for (int i = 0; i < 4; i++) a[i] += u[i] * w;
    }
    f32x4 og = *(const f32x4*)(Orig + rb);
#pragma unroll
    for (int i = 0; i < 4; i++) tile[nLoc][f + i] = (a[i] + bv[i]) * og[i];
  }
  __syncthreads();
  const int nl2 = t & 15, f0 = t >> 4;
#pragma unroll
  for (int q = 0; q < 32; q++) {
    const int ff = q * 16 + f0;
    out[((long)b * OUTF + ff) * (long)NN + n0 + nl2] = tile[nl2][ff];
  }
}

// ------------------------------- launcher ----------------------------------
extern "C" void kernel_launch(void* const* d_in, const int* in_sizes, int n_in,
                              void* d_out, int out_size, void* d_ws,
                              size_t ws_size, hipStream_t stream) {
  const float* x = (const float*)d_in[0];
  const float* W1 = (const float*)d_in[1];
  const float* b1 = (const float*)d_in[2];
  const float* W2 = (const float*)d_in[3];
  const float* b2 = (const float*)d_in[4];
  const float* Wl = (const float*)d_in[5];
  const float* bl = (const float*)d_in[6];
  float* out = (float*)d_out;

  uint8_t* ws = (uint8_t*)d_ws;
  size_t off = 0;
  auto alloc = [&](size_t bytes) -> void* {
    void* p = ws + off;
    off += (bytes + 255) & ~(size_t)255;
    return p;
  };
  // Lifetimes: xt [prep..gemm_o], xa [prep..gemm_h], h [gemm_h..gemm2],
  //            origin [gemm_o..stencil2], g2 [gemm2..stencil2].
  bf16* xt = (bf16*)alloc((size_t)NB * NN * CIN * 2);   // 50.3 MB, g2 aliases
  bf16* xa = (bf16*)alloc((size_t)NB * NN * CIN * 2);   // 50.3 MB, origin aliases
  bf16* hb = (bf16*)alloc((size_t)NB * NN * HIDF * 2);  // 50.3 MB
  bf16* w1t = (bf16*)alloc((size_t)HIDF * CIN * 2);     // 4.7 MB
  bf16* w2t = (bf16*)alloc((size_t)OUTF * HIDF * 2);    // 1.6 MB
  bf16* wlt = (bf16*)alloc((size_t)OUTF * CIN * 2);     // 1.6 MB  (~159 MB)
  float* origin = (float*)xa;  // 33.5 MB into xa's 50.3 (xa dead post gemm_h)
  float* g2 = (float*)xt;      // 33.5 MB into xt's 50.3 (xt dead post gemm_o)

  prep<<<XTILES + W1TILES + W2TILES + WLTILES, 256, 0, stream>>>(
      x, W1, W2, Wl, xt, xa, w1t, w2t, wlt);

  // h = relu(xa @ W1 + b1) + xt   (stencil1 folded away algebraically)
  gemm_h<<<dim3(NN / 128, HIDF / 128, NB), 256, 0, stream>>>(xa, w1t, xt, hb,
                                                             b1);
  // origin = xt @ Wl + bl  (overwrites xa slot)
  gemm_f32<true><<<dim3(NN / 128, OUTF / 128, NB), 256, 0, stream>>>(
      xt, wlt, origin, bl);
  // g2 = h @ W2  (overwrites xt slot)
  gemm_f32<false><<<dim3(NN / 128, OUTF / 128, NB), 256, 0, stream>>>(
      hb, w2t, g2, nullptr);
  // out = (Agg(g2)+b2) * origin, transposed to [B][OUT][N]
  stencil2<<<dim3(256, NB), 256, 0, stream>>>(g2, origin, b2, out);
}

// Round 4
// 372.302 us; speedup vs baseline: 1.2350x; 1.2350x over previous
//
#include <hip/hip_runtime.h>
#include <hip/hip_bf16.h>
#include <stdint.h>

// ---------------------------------------------------------------------------
// SGI grid-GCN head on MI355X.  Round 4:
//  - Round-3 algebra kept: xa = Agg(x) in prep, h = relu(xa@W1+b1)+xt in
//    gemm epilogue (no stencil1, no g1).
//  - prep REWRITTEN: 64x64 tiles, float4 stencil loads, ds_write_b128 LDS
//    staging, XOR-swizzled transpose reads, 16B/lane bf16x8 stores,
//    XCD-banded block decode (halo stays in-XCD L2).  Was 2.2 TB/s with
//    scalar loads + 2B stores; target >4.5 TB/s.
//  5 dispatches: prep, gemm_h, gemm_o, gemm2, stencil2.
// ---------------------------------------------------------------------------

typedef __bf16 bf16;
typedef float f32x4 __attribute__((ext_vector_type(4)));
typedef bf16 bf16x8 __attribute__((ext_vector_type(8)));

#define NB 4
#define NN 4096
#define CIN 1536
#define HIDF 1536
#define OUTF 512

__device__ __forceinline__ float degree_of(int n) {
  const int x = n & 63, y = n >> 6;
  return 1.0f + (x > 0) + (x < 63) + (y > 0) + (y < 63);
}
__device__ __forceinline__ float deg2(int gx, int gy) {
  return 1.0f + (gx > 0) + (gx < 63) + (gy > 0) + (gy < 63);
}

// ------------------------------- prep ---------------------------------------
// Block = 256 threads, one 64(c) x 64(n) tile.
//   x blocks   : 6144 (xcd-banded: nt = (B&7)*8 + slot%8)
//   W1 blocks  : 576, W2: 192, Wl: 192   -> grid 7104
// Phase A: float4 loads along n, stencil in registers, fp32 -> LDS b128
//          (chunk-swizzled: chunk = tx ^ (2*((c>>3)&7))).
// Phase B: transpose read (2-way bank alias = free), bf16x8 16B stores,
//          8 lanes form 128B contiguous runs per node row.
#define XBLK 6144
#define W1BLK 576
#define W2BLK 192

__global__ __launch_bounds__(256) void prep(
    const float* __restrict__ x, const float* __restrict__ W1,
    const float* __restrict__ W2, const float* __restrict__ Wl,
    bf16* __restrict__ xt, bf16* __restrict__ xa, bf16* __restrict__ w1t,
    bf16* __restrict__ w2t, bf16* __restrict__ wlt) {
  __shared__ float vt[64 * 64];
  __shared__ float at[64 * 64];
  const int B = blockIdx.x, t = threadIdx.x;
  const int tx = t & 15, ty = t >> 4;      // load phase: n4 = tx*4, c = ty*4+cc
  const int lane = t & 63, w = t >> 6;     // store phase
  const int u = lane & 7, n3 = lane >> 3;  // c-slot / n-subrow

  if (B < XBLK) {
    const int slot = B >> 3;
    const int nt = (B & 7) * 8 + (slot & 7);     // grid row, XCD-banded
    const int ct = (slot >> 3) % 24;
    const int bb = (slot >> 3) / 24;
    const int gy = nt;
    const int n0 = nt * 64, c0 = ct * 64;
    const float* xb = x + (long)bb * CIN * NN;
#pragma unroll
    for (int cc = 0; cc < 4; cc++) {
      const int cl = ty * 4 + cc;
      const float* row = xb + (long)(c0 + cl) * NN + n0;
      const int nb = tx * 4;
      f32x4 v = *(const f32x4*)(row + nb);
      f32x4 up = {0.f, 0.f, 0.f, 0.f};
      f32x4 dn = {0.f, 0.f, 0.f, 0.f};
      if (gy > 0) up = *(const f32x4*)(row + nb - 64);
      if (gy < 63) dn = *(const f32x4*)(row + nb + 64);
      const float lf = (tx > 0) ? row[nb - 1] : 0.f;
      const float rt = (tx < 15) ? row[nb + 4] : 0.f;
      f32x4 a;
#pragma unroll
      for (int i = 0; i < 4; i++) {
        const int gx = nb + i;
        const float degn = deg2(gx, gy);
        float s = v[i] * (1.0f / degn);
        const float lv = (i == 0) ? lf : v[i - 1];
        const float rv = (i == 3) ? rt : v[i + 1];
        if (gx > 0) s += lv * rsqrtf(degn * deg2(gx - 1, gy));
        if (gx < 63) s += rv * rsqrtf(degn * deg2(gx + 1, gy));
        if (gy > 0) s += up[i] * rsqrtf(degn * deg2(gx, gy - 1));
        if (gy < 63) s += dn[i] * rsqrtf(degn * deg2(gx, gy + 1));
        a[i] = s;
      }
      const int chunk = tx ^ (2 * ((cl >> 3) & 7));
      *(f32x4*)&vt[cl * 64 + chunk * 4] = v;
      *(f32x4*)&at[cl * 64 + chunk * 4] = a;
    }
    __syncthreads();
    bf16* xtb = xt + (long)bb * NN * CIN;
    bf16* xab = xa + (long)bb * NN * CIN;
#pragma unroll
    for (int q = 0; q < 4; q++) {
      const int j = q * 4 + w;           // 0..15
      const int arr = j & 1, r = j >> 1; // array / n-row group
      const int nl = n3 + 8 * r;
      const float* s = arr ? at : vt;
      bf16x8 o;
#pragma unroll
      for (int jj = 0; jj < 8; jj++) {
        const int cl = u * 8 + jj;
        const int col = nl ^ (8 * ((cl >> 3) & 7));
        o[jj] = (bf16)s[cl * 64 + col];
      }
      bf16* outp = arr ? xab : xtb;
      *(bf16x8*)&outp[(long)(n0 + nl) * CIN + c0 + u * 8] = o;
    }
  } else {
    // ---- weight transpose: src [K][F] fp32 -> dst [F][K] bf16 ----
    int B2 = B - XBLK;
    const float* srcp;
    bf16* dstp;
    int Fdim, Kd, nt, ct;
    if (B2 < W1BLK) {
      nt = B2 / 24; ct = B2 % 24; srcp = W1; dstp = w1t; Fdim = HIDF; Kd = CIN;
    } else if (B2 < W1BLK + W2BLK) {
      const int l = B2 - W1BLK;
      nt = l / 24; ct = l % 24; srcp = W2; dstp = w2t; Fdim = OUTF; Kd = HIDF;
    } else {
      const int l = B2 - W1BLK - W2BLK;
      nt = l / 24; ct = l % 24; srcp = Wl; dstp = wlt; Fdim = OUTF; Kd = CIN;
    }
    const int n0 = nt * 64, c0 = ct * 64;
#pragma unroll
    for (int cc = 0; cc < 4; cc++) {
      const int cl = ty * 4 + cc;
      const float* row = srcp + (long)(c0 + cl) * Fdim + n0;
      f32x4 v = *(const f32x4*)(row + tx * 4);
      const int chunk = tx ^ (2 * ((cl >> 3) & 7));
      *(f32x4*)&vt[cl * 64 + chunk * 4] = v;
    }
    __syncthreads();
#pragma unroll
    for (int q = 0; q < 2; q++) {
      const int r = q * 4 + w;           // 0..7
      const int nl = n3 + 8 * r;
      bf16x8 o;
#pragma unroll
      for (int jj = 0; jj < 8; jj++) {
        const int cl = u * 8 + jj;
        const int col = nl ^ (8 * ((cl >> 3) & 7));
        o[jj] = (bf16)vt[cl * 64 + col];
      }
      *(bf16x8*)&dstp[(long)(n0 + nl) * Kd + c0 + u * 8] = o;
    }
  }
}

// ------------------------------- GEMM core ---------------------------------
__device__ __forceinline__ void async_copy16(const void* g, void* l) {
  __builtin_amdgcn_global_load_lds(
      (const __attribute__((address_space(1))) void*)g,
      (__attribute__((address_space(3))) void*)l, 16, 0, 0);
}

struct GemmCtx {
  f32x4 acc[4][4];
  int wave, lane, wm, wn, quad, l15;
};

__device__ __forceinline__ void gemm_init(GemmCtx& cx, int t) {
  cx.wave = t >> 6;
  cx.lane = t & 63;
  cx.wm = (cx.wave & 1) * 64;
  cx.wn = (cx.wave >> 1) * 64;
  cx.quad = cx.lane >> 4;
  cx.l15 = cx.lane & 15;
#pragma unroll
  for (int i = 0; i < 4; i++)
#pragma unroll
    for (int j = 0; j < 4; j++) cx.acc[i][j] = {0.f, 0.f, 0.f, 0.f};
}

template <int K>
__device__ __forceinline__ void gemm_kloop(GemmCtx& cx, const bf16* Ab,
                                           const bf16* Bb, bf16* As,
                                           bf16* Bs) {
  const int r = cx.lane >> 3, c8 = cx.lane & 7;
  const int fchunk = c8 ^ r;
  for (int kt = 0; kt < K; kt += 64) {
#pragma unroll
    for (int i = 0; i < 4; i++) {
      const int row = i * 32 + cx.wave * 8;
      async_copy16(Ab + (long)(row + r) * K + kt + fchunk * 8, &As[row * 64]);
      async_copy16(Bb + (long)(row + r) * K + kt + fchunk * 8, &Bs[row * 64]);
    }
    __syncthreads();
#pragma unroll
    for (int kk = 0; kk < 2; kk++) {
      const int q = kk * 4 + cx.quad;
      bf16x8 af[4], bfv[4];
#pragma unroll
      for (int mr = 0; mr < 4; mr++) {
        const int m = cx.wm + mr * 16 + cx.l15;
        af[mr] = *(const bf16x8*)&As[m * 64 + (q ^ (m & 7)) * 8];
      }
#pragma unroll
      for (int nc = 0; nc < 4; nc++) {
        const int n = cx.wn + nc * 16 + cx.l15;
        bfv[nc] = *(const bf16x8*)&Bs[n * 64 + (q ^ (n & 7)) * 8];
      }
#pragma unroll
      for (int mr = 0; mr < 4; mr++)
#pragma unroll
        for (int nc = 0; nc < 4; nc++)
          cx.acc[mr][nc] = __builtin_amdgcn_mfma_f32_16x16x32_bf16(
              af[mr], bfv[nc], cx.acc[mr][nc], 0, 0, 0);
    }
    __syncthreads();
  }
}

// h = bf16( relu(xa @ w1t^T + b1) + xt )   [B][NN][HIDF]
__global__ __launch_bounds__(256) void gemm_h(
    const bf16* __restrict__ xa, const bf16* __restrict__ w1t,
    const bf16* __restrict__ xt, bf16* __restrict__ h,
    const float* __restrict__ b1) {
  __shared__ bf16 As[128 * 64];
  __shared__ bf16 Bs[128 * 64];
  GemmCtx cx;
  gemm_init(cx, threadIdx.x);
  const int m0 = blockIdx.x * 128, n0 = blockIdx.y * 128, z = blockIdx.z;
  gemm_kloop<CIN>(cx, xa + (long)z * NN * CIN + (long)m0 * CIN,
                  w1t + (long)n0 * CIN, As, Bs);
  const bf16* Xb = xt + (long)z * NN * HIDF;
  bf16* Cb = h + (long)z * NN * HIDF;
#pragma unroll
  for (int mr = 0; mr < 4; mr++)
#pragma unroll
    for (int nc = 0; nc < 4; nc++) {
      const int gn = n0 + cx.wn + nc * 16 + cx.l15;
      const float bv = b1[gn];
#pragma unroll
      for (int j = 0; j < 4; j++) {
        const int gm = m0 + cx.wm + mr * 16 + cx.quad * 4 + j;
        float v = cx.acc[mr][nc][j] + bv;
        v = v > 0.f ? v : 0.f;
        Cb[(long)gm * HIDF + gn] = (bf16)(v + (float)Xb[(long)gm * HIDF + gn]);
      }
    }
}

// fp32-out GEMM (gemm_o with bias, gemm2 without).  K = 1536 both.
template <bool ADD_BIAS>
__global__ __launch_bounds__(256) void gemm_f32(
    const bf16* __restrict__ A, const bf16* __restrict__ Bw,
    float* __restrict__ C, const float* __restrict__ bias) {
  __shared__ bf16 As[128 * 64];
  __shared__ bf16 Bs[128 * 64];
  GemmCtx cx;
  gemm_init(cx, threadIdx.x);
  const int m0 = blockIdx.x * 128, n0 = blockIdx.y * 128, z = blockIdx.z;
  gemm_kloop<CIN>(cx, A + (long)z * NN * CIN + (long)m0 * CIN,
                  Bw + (long)n0 * CIN, As, Bs);
  float* Cb = C + (long)z * NN * OUTF;
#pragma unroll
  for (int mr = 0; mr < 4; mr++)
#pragma unroll
    for (int nc = 0; nc < 4; nc++) {
      const int gn = n0 + cx.wn + nc * 16 + cx.l15;
      float bv = 0.f;
      if (ADD_BIAS) bv = bias[gn];
#pragma unroll
      for (int j = 0; j < 4; j++) {
        const int gm = m0 + cx.wm + mr * 16 + cx.quad * 4 + j;
        Cb[(long)gm * OUTF + gn] = cx.acc[mr][nc][j] + bv;
      }
    }
}

// ------------------------------- stencil2 ----------------------------------
// out[b][f][n] = (Agg(G2)[n][f] + b2[f]) * Origin[n][f]; transpose via LDS.
__global__ __launch_bounds__(256) void stencil2(
    const float* __restrict__ G2, const float* __restrict__ Orig,
    const float* __restrict__ b2, float* __restrict__ out) {
  __shared__ float tile[16][513];
  const int blk = blockIdx.x;                        // 256 strips
  const int s = ((blk & 7) << 5) + (blk >> 3);       // XCD-contiguous
  const int n0 = s * 16, b = blockIdx.y;
  const int t = threadIdx.x;
  const int fq = t & 127, nl = t >> 7;
  const int f = fq * 4;
  const f32x4 bv = *(const f32x4*)(b2 + f);
#pragma unroll
  for (int p = 0; p < 8; p++) {
    const int nLoc = p * 2 + nl;
    const int n = n0 + nLoc;
    const int gx = n & 63, gy = n >> 6;
    const float degn = degree_of(n);
    const float ws = 1.0f / degn;
    const long rb = ((long)b * NN + n) * (long)OUTF + f;
    f32x4 g = *(const f32x4*)(G2 + rb);
    f32x4 a;
#pragma unroll
    for (int i = 0; i < 4; i++) a[i] = g[i] * ws;
    if (gx > 0) {
      const float w = rsqrtf(degn * degree_of(n - 1));
      f32x4 u = *(const f32x4*)(G2 + rb - OUTF);
#pragma unroll
      for (int i = 0; i < 4; i++) a[i] += u[i] * w;
    }
    if (gx < 63) {
      const float w = rsqrtf(degn * degree_of(n + 1));
      f32x4 u = *(const f32x4*)(G2 + rb + OUTF);
#pragma unroll
      for (int i = 0; i < 4; i++) a[i] += u[i] * w;
    }
    if (gy > 0) {
      const float w = rsqrtf(degn * degree_of(n - 64));
      f32x4 u = *(const f32x4*)(G2 + rb - 64L * OUTF);
#pragma unroll
      for (int i = 0; i < 4; i++) a[i] += u[i] * w;
    }
    if (gy < 63) {
      const float w = rsqrtf(degn * degree_of(n + 64));
      f32x4 u = *(const f32x4*)(G2 + rb + 64L * OUTF);
#pragma unroll
      for (int i = 0; i < 4; i++) a[i] += u[i] * w;
    }
    f32x4 og = *(const f32x4*)(Orig + rb);
#pragma unroll
    for (int i = 0; i < 4; i++) tile[nLoc][f + i] = (a[i] + bv[i]) * og[i];
  }
  __syncthreads();
  const int nl2 = t & 15, f0 = t >> 4;
#pragma unroll
  for (int q = 0; q < 32; q++) {
    const int ff = q * 16 + f0;
    out[((long)b * OUTF + ff) * (long)NN + n0 + nl2] = tile[nl2][ff];
  }
}

// ------------------------------- launcher ----------------------------------
extern "C" void kernel_launch(void* const* d_in, const int* in_sizes, int n_in,
                              void* d_out, int out_size, void* d_ws,
                              size_t ws_size, hipStream_t stream) {
  const float* x = (const float*)d_in[0];
  const float* W1 = (const float*)d_in[1];
  const float* b1 = (const float*)d_in[2];
  const float* W2 = (const float*)d_in[3];
  const float* b2 = (const float*)d_in[4];
  const float* Wl = (const float*)d_in[5];
  const float* bl = (const float*)d_in[6];
  float* out = (float*)d_out;

  uint8_t* ws = (uint8_t*)d_ws;
  size_t off = 0;
  auto alloc = [&](size_t bytes) -> void* {
    void* p = ws + off;
    off += (bytes + 255) & ~(size_t)255;
    return p;
  };
  // Lifetimes: xt [prep..gemm_o], xa [prep..gemm_h], h [gemm_h..gemm2],
  //            origin [gemm_o..stencil2] (aliases xa), g2 [gemm2..stencil2]
  //            (aliases xt).
  bf16* xt = (bf16*)alloc((size_t)NB * NN * CIN * 2);   // 50.3 MB
  bf16* xa = (bf16*)alloc((size_t)NB * NN * CIN * 2);   // 50.3 MB
  bf16* hb = (bf16*)alloc((size_t)NB * NN * HIDF * 2);  // 50.3 MB
  bf16* w1t = (bf16*)alloc((size_t)HIDF * CIN * 2);     // 4.7 MB
  bf16* w2t = (bf16*)alloc((size_t)OUTF * HIDF * 2);    // 1.6 MB
  bf16* wlt = (bf16*)alloc((size_t)OUTF * CIN * 2);     // 1.6 MB (~159 MB)
  float* origin = (float*)xa;
  float* g2 = (float*)xt;

  prep<<<XBLK + W1BLK + 2 * W2BLK, 256, 0, stream>>>(x, W1, W2, Wl, xt, xa,
                                                     w1t, w2t, wlt);
  // h = relu(xa @ W1 + b1) + xt
  gemm_h<<<dim3(NN / 128, HIDF / 128, NB), 256, 0, stream>>>(xa, w1t, xt, hb,
                                                             b1);
  // origin = xt @ Wl + bl  (overwrites xa slot — xa dead after gemm_h)
  gemm_f32<true><<<dim3(NN / 128, OUTF / 128, NB), 256, 0, stream>>>(
      xt, wlt, origin, bl);
  // g2 = h @ W2  (overwrites xt slot — xt dead after gemm_o)
  gemm_f32<false><<<dim3(NN / 128, OUTF / 128, NB), 256, 0, stream>>>(
      hb, w2t, g2, nullptr);
  // out = (Agg(g2)+b2) * origin, transposed to [B][OUT][N]
  stencil2<<<dim3(256, NB), 256, 0, stream>>>(g2, origin, b2, out);
}